// Round 14
// baseline (194.930 us; speedup 1.0000x reference)
//
#include <hip/hip_runtime.h>
#include <stdint.h>

// CONV-KNRM fused pipeline for MI355X (gfx950). Round 28 = R26/27 (179.4us)
// + TWO changes:
//  (1) k_pool: grp-loop (exactly 2 iters) fully unrolled; BOTH 12-load fp8
//      gather batches hoisted up front (24 loads in flight, sched_barrier-
//      pinned) -> batch B latency hides under batch A compute. VGPR need
//      ~110-125 -> __launch_bounds__(256,2) (allocator budget ~= 512/(2*arg):
//      arg2->128 fits, arg3's ~85 would spill). Residency 3->2 blocks but
//      total in-flight lines unchanged; the serial-latency term vanishes.
//  (2) k_project: A bf16 convert via v_cvt_pk_bf16_f32 (80 insts vs ~640
//      scalar-magic VALU ops per thread; bit-identical RNE).
// Spill tripwire: k_pool WRITE_SIZE must stay ~6.3MB.
// B=32, Q=16, D=4096, V=30000, C=128, EM=300, NBINS=11.

typedef short short8 __attribute__((ext_vector_type(8)));
typedef unsigned short ushort8 __attribute__((ext_vector_type(8)));
typedef float floatx4 __attribute__((ext_vector_type(4)));
typedef float floatx2 __attribute__((ext_vector_type(2)));

#define NB_V 30000

__device__ __forceinline__ unsigned short f32_bf16(float f) {
  union { float f; uint32_t u; } v; v.f = f;
  return (unsigned short)((v.u + 0x7FFFu + ((v.u >> 16) & 1u)) >> 16);
}
__device__ __forceinline__ float bits_f32(uint32_t u) {
  union { uint32_t u; float f; } v; v.u = u; return v.f;
}

// HW packed f32x2 -> bf16x2 (RNE; lo16=bf16(a), hi16=bf16(b))
__device__ __forceinline__ uint32_t cvt_pk_bf16(float a, float b) {
  uint32_t r;
  asm("v_cvt_pk_bf16_f32 %0, %1, %2" : "=v"(r) : "v"(a), "v"(b));
  return r;
}

// ---- fp8 e4m3 (OCP on gfx950) HW conversions ----
__device__ __forceinline__ floatx2 fp8x2_lo(uint32_t w) {
  return __builtin_amdgcn_cvt_pk_f32_fp8(w, false);   // bytes 0,1
}
__device__ __forceinline__ floatx2 fp8x2_hi(uint32_t w) {
  return __builtin_amdgcn_cvt_pk_f32_fp8(w, true);    // bytes 2,3
}
__device__ __forceinline__ unsigned char f32_fp8(float f) {
  return (unsigned char)(__builtin_amdgcn_cvt_pk_fp8_f32(f, f, 0, false) & 0xFF);
}

// lgkmcnt-only barrier: orders LDS reads/writes across waves without
// draining vmcnt (global stores / prefetched loads stay in flight).
__device__ __forceinline__ void barrier_lds() {
  asm volatile("s_waitcnt lgkmcnt(0)\n\ts_barrier" ::: "memory");
}

// ------------- W -> bf16 (768x320, zero-padded), tiny -------------
__global__ __launch_bounds__(256) void k_convert(
    const float* __restrict__ Wu, const float* __restrict__ Wb,
    const float* __restrict__ Wt,
    unsigned short* __restrict__ W_bf) {
  int u = blockIdx.x * 256 + threadIdx.x;
  if (u >= 768 * 40) return;
  int chg = u / 40, kc = u % 40;
  int seg = chg >> 7, ch = chg & 127;
  const float* Wsrc; int kw, jj;
  if (seg == 0)      { Wsrc = Wu; kw = 1; jj = 0; }
  else if (seg <= 2) { Wsrc = Wb; kw = 2; jj = seg - 1; }
  else               { Wsrc = Wt; kw = 3; jj = seg - 3; }
  const float* src = Wsrc + ((size_t)ch * kw + jj) * 300;
  int k0 = kc * 8;
  ushort8 o;
#pragma unroll
  for (int e = 0; e < 8; e++)
    o[e] = (k0 + e < 300) ? f32_bf16(src[k0 + e]) : (unsigned short)0;
  *(ushort8*)(W_bf + (size_t)chg * 320 + k0) = o;
}

// ---------------- Stage A: vocab projection GEMM ----------------
// grid = 1440 (240 mb-slots x 6 segs, mb>=235 idle). XCD-colocate:
// l=(bid%8)*180+bid/8. A read from wv f32 + HW cvt_pk_bf16 round (RNE,
// bit-identical to scalar magic). 128 rows x 128 cols, K=320. 4 quarter-
// phases of 32 cols; LDS 32ch x 328 = 20,992B. Output P is fp8 e4m3.
__global__ __launch_bounds__(256) void k_project(
    const float* __restrict__ wv,
    const unsigned short* __restrict__ W_bf,
    unsigned char* __restrict__ P) {
  __shared__ __align__(16) unsigned short wlds[32 * 328];   // 20,992 B
  int tid = threadIdx.x;
  int p = blockIdx.x;
  int l = (p & 7) * 180 + (p >> 3);      // bijective 0..1439
  int mb = l / 6, seg = l - mb * 6;
  if (mb >= 235) return;
  int wave = tid >> 6, lane = tid & 63;
  int li = lane & 15, quad = lane >> 4;
  int rows0 = mb * 128 + wave * 32;

  // A-fragment register cache from f32 wv: both 16-row tiles, 10 K-steps.
  // K-tail clamp at 296: K=296..299 are valid; dup slots hit W zero-pad.
  short8 af[2][10];
  {
    int r0 = rows0 + li, r1 = rows0 + 16 + li;
    const float* a0 = wv + (size_t)(r0 < NB_V ? r0 : NB_V - 1) * 300;
    const float* a1 = wv + (size_t)(r1 < NB_V ? r1 : NB_V - 1) * 300;
#pragma unroll
    for (int ks = 0; ks < 10; ks++) {
      int k0 = ks * 32 + quad * 8;
      int ka = k0 > 296 ? 296 : k0;          // float4-aligned, in-bounds
      int kb = k0 + 4 > 296 ? 296 : k0 + 4;
      float4 x0 = *(const float4*)(a0 + ka);
      float4 x1 = *(const float4*)(a0 + kb);
      float4 y0 = *(const float4*)(a1 + ka);
      float4 y1 = *(const float4*)(a1 + kb);
      union { uint32_t u[4]; short8 s; } c0, c1;
      c0.u[0] = cvt_pk_bf16(x0.x, x0.y); c0.u[1] = cvt_pk_bf16(x0.z, x0.w);
      c0.u[2] = cvt_pk_bf16(x1.x, x1.y); c0.u[3] = cvt_pk_bf16(x1.z, x1.w);
      c1.u[0] = cvt_pk_bf16(y0.x, y0.y); c1.u[1] = cvt_pk_bf16(y0.z, y0.w);
      c1.u[2] = cvt_pk_bf16(y1.x, y1.y); c1.u[3] = cvt_pk_bf16(y1.z, y1.w);
      af[0][ks] = c0.s;
      af[1][ks] = c1.s;
    }
  }
  const unsigned short* wseg = W_bf + (size_t)seg * 128 * 320;

  for (int h = 0; h < 4; h++) {
    if (h) barrier_lds();   // prev quarter's ds_reads done before restage
    {  // stage 32 channels x 320 K from W_bf (uint4; dest row = 41 chunks)
#pragma unroll
      for (int i = 0; i < 5; i++) {
        int idx = i * 256 + tid;        // source chunk 0..1279
        int ch = idx / 40, kc = idx - ch * 40;
        uint4 v = *(const uint4*)(wseg + (size_t)(h * 32 + ch) * 320 + kc * 8);
        *(uint4*)(wlds + (ch * 41 + kc) * 8) = v;
      }
    }
    barrier_lds();

    floatx4 acc[2][2];
#pragma unroll
    for (int rt = 0; rt < 2; rt++)
#pragma unroll
      for (int ct = 0; ct < 2; ct++) acc[rt][ct] = (floatx4){0.f, 0.f, 0.f, 0.f};

#pragma unroll
    for (int ks = 0; ks < 10; ks++) {
      int ck = ks * 32 + quad * 8;
#pragma unroll
      for (int ct = 0; ct < 2; ct++) {
        short8 bf = *(const short8*)&wlds[(ct * 16 + li) * 328 + ck];
        acc[0][ct] = __builtin_amdgcn_mfma_f32_16x16x32_bf16(af[0][ks], bf, acc[0][ct], 0, 0, 0);
        acc[1][ct] = __builtin_amdgcn_mfma_f32_16x16x32_bf16(af[1][ks], bf, acc[1][ct], 0, 0, 0);
      }
    }
#pragma unroll
    for (int rt = 0; rt < 2; rt++)
#pragma unroll
      for (int ct = 0; ct < 2; ct++)
#pragma unroll
        for (int r = 0; r < 4; r++) {
          int row = rows0 + rt * 16 + quad * 4 + r;   // < 30080, P padded
          P[(size_t)row * 768 + seg * 128 + h * 32 + ct * 16 + li] =
              f32_fp8(acc[rt][ct][r]);
        }
  }
}

// ---------------- query n-gram vectors (tiny: 384 waves) ----------------
template <int KK>
__device__ __forceinline__ void build_qvec4(
    int b, int type, int l0,
    const int* __restrict__ tokens, const unsigned char* __restrict__ P,
    const float* __restrict__ bias,
    unsigned short* __restrict__ vec, float* __restrict__ inv, int lane) {
  const int segBase[3] = {0, 128, 384};
  int sub = lane >> 4, li = lane & 15;
  int l = l0 + sub;
  size_t row = (size_t)(b * 3 + type) * 16 + l;
  uint4 o = make_uint4(0u, 0u, 0u, 0u);
  float invv = 0.0f;
  if (l + KK <= 16) {
    float v[8];
    {
      float4 b0 = *(const float4*)(bias + li * 8);
      float4 b1 = *(const float4*)(bias + li * 8 + 4);
      v[0] = b0.x; v[1] = b0.y; v[2] = b0.z; v[3] = b0.w;
      v[4] = b1.x; v[5] = b1.y; v[6] = b1.z; v[7] = b1.w;
    }
    const int* tk = tokens + (size_t)b * 16 + l;
    const unsigned char* pb = P + segBase[type] + li * 8;
#pragma unroll
    for (int j = 0; j < KK; j++) {
      uint2 pp = *(const uint2*)(pb + (size_t)tk[j] * 768 + j * 128);
      floatx2 f0 = fp8x2_lo(pp.x), f1 = fp8x2_hi(pp.x);
      floatx2 f2 = fp8x2_lo(pp.y), f3 = fp8x2_hi(pp.y);
      v[0] += f0.x; v[1] += f0.y; v[2] += f1.x; v[3] += f1.y;
      v[4] += f2.x; v[5] += f2.y; v[6] += f3.x; v[7] += f3.y;
    }
    uint32_t w[4];
    float s = 0.0f;
#pragma unroll
    for (int e = 0; e < 4; e++) {
      float f0 = fmaxf(v[2 * e], 0.0f) + 1e-9f;
      float f1 = fmaxf(v[2 * e + 1], 0.0f) + 1e-9f;
      uint32_t wd = cvt_pk_bf16(f0, f1);   // lo=bf16(f0), hi=bf16(f1)
      w[e] = wd;
      float g0 = bits_f32(wd << 16);
      float g1 = bits_f32(wd & 0xFFFF0000u);
      s = fmaf(g0, g0, fmaf(g1, g1, s));
    }
#pragma unroll
    for (int off = 1; off < 16; off <<= 1) s += __shfl_xor(s, off);
    invv = rsqrtf(s);
    o = make_uint4(w[0], w[1], w[2], w[3]);
  }
  *(uint4*)(vec + row * 128 + li * 8) = o;
  if (li == 0) inv[row] = invv;
}

__global__ __launch_bounds__(256) void k_qvec(
    const int* __restrict__ qtok, const unsigned char* __restrict__ P,
    const float* __restrict__ bu, const float* __restrict__ bb,
    const float* __restrict__ bt,
    unsigned short* __restrict__ qvec, float* __restrict__ qinv) {
  int wid = blockIdx.x * 4 + (threadIdx.x >> 6);  // 0..383
  int lane = threadIdx.x & 63;
  int b = wid / 12;
  int rem = wid % 12;
  int type = rem / 4, l0 = (rem % 4) * 4;
  if (type == 0)      build_qvec4<1>(b, 0, l0, qtok, P, bu, qvec, qinv, lane);
  else if (type == 1) build_qvec4<2>(b, 1, l0, qtok, P, bb, qvec, qinv, lane);
  else                build_qvec4<3>(b, 2, l0, qtok, P, bt, qvec, qinv, lane);
}

// ------- Stage C: fused doc-build-in-registers + sim MFMA + pooling -------
// LPT grid: bid/1024 -> dt=2,1,0; b = (bid%1024)/32, chunk = bid%32.
// pacc ALIASES qlds. R28: BOTH grp-iterations' gather batches hoisted up
// front (24 uint2 loads in flight, sched_barrier-pinned); batch B's latency
// hides under batch A's compute. Packed-f32 unpack, cvt_pk_bf16, packed bins.
template <int KK>
__device__ __forceinline__ void pool_body(
    int b, int chunk, const int* __restrict__ dtok,
    const unsigned char* __restrict__ P, const float* __restrict__ bias,
    const unsigned short* qlds, const float* qil, float* pacc,
    float* __restrict__ pout, int tid) {
  constexpr int dt = KK - 1;
  constexpr int segB = (dt == 0) ? 0 : (dt == 1) ? 128 : 384;
  const int wave = tid >> 6, lane = tid & 63;
  const int li = lane & 15, quad = lane >> 4;
  const int validD = 4096 - dt;

  float acc0[3];                 // bin 0 (sigma=0.001)
  floatx2 acc2[3][5];            // bins (1,2),(3,4),(5,6),(7,8),(9,10)
#pragma unroll
  for (int qt = 0; qt < 3; qt++) {
    acc0[qt] = 0.f;
#pragma unroll
    for (int p = 0; p < 5; p++) acc2[qt][p] = (floatx2){0.f, 0.f};
  }

  // Two grp iterations (grp = wave, wave+4) fully unrolled; gathers for BOTH
  // issued before any unpack.
  const int d0A = chunk * 128 + wave * 16;
  const int d0B = d0A + 64;
  const bool okA = (d0A + li + KK <= 4096);
  const bool okB = (d0B + li + KK <= 4096);
  int toxA[KK], toxB[KK];
#pragma unroll
  for (int j = 0; j < KK; j++) {
    int ta = d0A + li + j; if (ta > 4095) ta = 4095;
    int tb = d0B + li + j; if (tb > 4095) tb = 4095;
    toxA[j] = dtok[(size_t)b * 4096 + ta];
    toxB[j] = dtok[(size_t)b * 4096 + tb];
  }
  uint2 ppA[KK][4], ppB[KK][4];
#pragma unroll
  for (int j = 0; j < KK; j++) {
    const unsigned char* ra = P + (size_t)toxA[j] * 768 + segB + j * 128 + quad * 8;
    const unsigned char* rb = P + (size_t)toxB[j] * 768 + segB + j * 128 + quad * 8;
#pragma unroll
    for (int sl = 0; sl < 4; sl++) {
      ppA[j][sl] = *(const uint2*)(ra + sl * 32);
      ppB[j][sl] = *(const uint2*)(rb + sl * 32);
    }
  }
  // Pin: all 24 loads issued back-to-back before any unpack.
  __builtin_amdgcn_sched_barrier(0);

  auto proc = [&](const uint2 (&pp)[KK][4], int d0, bool ok) {
    float sq = 0.f;
    short8 af[4];
#pragma unroll
    for (int sl = 0; sl < 4; sl++) {
      int co = sl * 32 + quad * 8;       // channel (byte) offset within segment
      floatx2 v2[4];
      {
        const floatx2* b2 = (const floatx2*)(bias + co);
        v2[0] = b2[0]; v2[1] = b2[1]; v2[2] = b2[2]; v2[3] = b2[3];
      }
#pragma unroll
      for (int j = 0; j < KK; j++) {
        uint2 pq = pp[j][sl];
        v2[0] += fp8x2_lo(pq.x); v2[1] += fp8x2_hi(pq.x);
        v2[2] += fp8x2_lo(pq.y); v2[3] += fp8x2_hi(pq.y);
      }
      union { uint32_t u[4]; short8 s8; } pk;
#pragma unroll
      for (int e = 0; e < 4; e++) {
        float f0 = fmaxf(v2[e].x, 0.0f) + 1e-9f;
        float f1 = fmaxf(v2[e].y, 0.0f) + 1e-9f;
        uint32_t wd = cvt_pk_bf16(f0, f1);
        pk.u[e] = wd;
        float g0 = bits_f32(wd << 16);
        float g1 = bits_f32(wd & 0xFFFF0000u);
        sq = fmaf(g0, g0, fmaf(g1, g1, sq));
      }
      af[sl] = pk.s8;   // garbage rows are masked by validD below
    }
    sq += __shfl_xor(sq, 16);           // reduce over quads (same doc)
    sq += __shfl_xor(sq, 32);
    float invd = ok ? rsqrtf(sq) : 0.0f;
    float iv[4];
#pragma unroll
    for (int r = 0; r < 4; r++) iv[r] = __shfl(invd, quad * 4 + r);

#pragma unroll
    for (int qt = 0; qt < 3; qt++) {
      floatx4 sim = (floatx4){0.f, 0.f, 0.f, 0.f};
      const unsigned short* qb = qlds + (qt * 16 + li) * 136 + quad * 8;
      sim = __builtin_amdgcn_mfma_f32_16x16x32_bf16(af[0], *(const short8*)(qb), sim, 0, 0, 0);
      sim = __builtin_amdgcn_mfma_f32_16x16x32_bf16(af[1], *(const short8*)(qb + 32), sim, 0, 0, 0);
      sim = __builtin_amdgcn_mfma_f32_16x16x32_bf16(af[2], *(const short8*)(qb + 64), sim, 0, 0, 0);
      sim = __builtin_amdgcn_mfma_f32_16x16x32_bf16(af[3], *(const short8*)(qb + 96), sim, 0, 0, 0);
      float invq = qil[qt * 16 + li];
#pragma unroll
      for (int r = 0; r < 4; r++) {
        if (d0 + quad * 4 + r < validD) {
          float s = sim[r] * (invq * iv[r]);
          // bin 0 (sigma=0.001): exp underflows to 0 unless s ~ 1
          if (s > 0.9868f) {
            float t0 = s - 1.0f;
            acc0[qt] += __expf(t0 * t0 * -500000.0f);
          }
          // bins 1..10 packed: F=(f_i, f_{i+1}), M=(v^2c, v^2c^3), M*=c^4
          float y = s - 0.9f;
          float f = __expf(y * y * -50.0f);
          float v = __expf(fmaf(y, -20.0f, -2.0f));
          floatx2 F; F.x = f; F.y = f * v;
          float vv = v * v;
          floatx2 M; M.x = vv * 0.018315639f;        // v^2 e^-4
          M.y = M.x * 3.3546263e-4f;                 // v^2 e^-12
          const floatx2 C4 = {1.1253517e-7f, 1.1253517e-7f};  // e^-16
#pragma unroll
          for (int pi = 0; pi < 5; pi++) {
            acc2[qt][pi] += F;
            F *= M;
            M *= C4;
          }
        }
      }
    }
  };
  proc(ppA, d0A, okA);
  proc(ppB, d0B, okB);

  // pacc aliases qlds: ALL waves must finish their MFMA qlds reads before
  // any wave overwrites the buffer with partial accumulators.
  __syncthreads();
#pragma unroll
  for (int qt = 0; qt < 3; qt++) {
    {
      float v = acc0[qt];
      v += __shfl_xor(v, 16);
      v += __shfl_xor(v, 32);
      if (lane < 16) pacc[wave * 528 + (qt * 16 + lane) * 11 + 0] = v;
    }
#pragma unroll
    for (int p = 0; p < 5; p++) {
      float vx = acc2[qt][p].x, vy = acc2[qt][p].y;
      vx += __shfl_xor(vx, 16); vx += __shfl_xor(vx, 32);
      vy += __shfl_xor(vy, 16); vy += __shfl_xor(vy, 32);
      if (lane < 16) {
        pacc[wave * 528 + (qt * 16 + lane) * 11 + 2 * p + 1] = vx;
        pacc[wave * 528 + (qt * 16 + lane) * 11 + 2 * p + 2] = vy;
      }
    }
  }
  __syncthreads();
  for (int idx = tid; idx < 528; idx += 256)
    pout[idx] = pacc[idx] + pacc[528 + idx] + pacc[1056 + idx] + pacc[1584 + idx];
}

__global__ __launch_bounds__(256, 2) void k_pool(
    const int* __restrict__ dtok,
    const unsigned char* __restrict__ P,
    const float* __restrict__ bu, const float* __restrict__ bb,
    const float* __restrict__ bt,
    const unsigned short* __restrict__ qvec, const float* __restrict__ qinv,
    float* __restrict__ partial) {
  // qlds (13,056 B) doubles as pacc (8,448 B) after the main loop.
  __shared__ __align__(16) unsigned short qlds[48 * 136];   // 13,056 B
  __shared__ float qil[48];
  int bid = blockIdx.x;
  // LPT: heavy dt=2 first (bid 0..1023), then dt=1, then dt=0.
  int dt = 2 - (bid >> 10);
  int r = bid & 1023;
  int b = r >> 5, chunk = r & 31;
  int tid = threadIdx.x;
  for (int idx = tid; idx < 48 * 32; idx += 256) {
    int row = idx >> 5, kq = (idx & 31) * 4;
    *(uint2*)&qlds[row * 136 + kq] =
        *(const uint2*)(qvec + ((size_t)b * 48 + row) * 128 + kq);
  }
  if (tid < 48) qil[tid] = qinv[b * 48 + tid];
  __syncthreads();
  float* pacc = (float*)qlds;   // alias: safe via barrier in pool_body
  float* pout = partial + ((size_t)((b * 3 + dt) * 32) + chunk) * 528;
  if (dt == 0)      pool_body<1>(b, chunk, dtok, P, bu, qlds, qil, pacc, pout, tid);
  else if (dt == 1) pool_body<2>(b, chunk, dtok, P, bb, qlds, qil, pacc, pout, tid);
  else              pool_body<3>(b, chunk, dtok, P, bt, qlds, qil, pacc, pout, tid);
}

// ------- fused chunk-reduce + log + query-sum epilogue (one dispatch) -------
__global__ __launch_bounds__(256) void k_finale(const float* __restrict__ partial,
                                                float* __restrict__ out) {
  int idx = blockIdx.x * 256 + threadIdx.x;   // 50688 total
  if (idx >= 32 * 3 * 3 * 11 * 16) return;
  int q = idx & 15;
  int g = idx >> 4;                 // (b,qt,dt,bin), bin fastest
  int bin = g % 11; g /= 11;
  int dt = g % 3; g /= 3;
  int qt = g % 3; int b = g / 3;
  const float* p = partial + ((size_t)(b * 3 + dt) * 32) * 528 + (qt * 16 + q) * 11 + bin;
  float s = 0.f;
#pragma unroll
  for (int c = 0; c < 32; c++) s += p[c * 528];
  float t = (q < 16 - qt) ? 0.01f * logf(fmaxf(s, 1e-10f)) : 0.0f;
#pragma unroll
  for (int off = 1; off < 16; off <<= 1) t += __shfl_xor(t, off);
  if (q == 0) {
    const int p_of[3][3] = {{0, 2, 1}, {3, 5, 6}, {4, 7, 8}};
    out[b * 99 + p_of[qt][dt] * 11 + bin] = t;
  }
}

extern "C" void kernel_launch(void* const* d_in, const int* in_sizes, int n_in,
                              void* d_out, int out_size, void* d_ws, size_t ws_size,
                              hipStream_t stream) {
  const int* qtok = (const int*)d_in[0];
  const int* dtok = (const int*)d_in[1];
  // d_in[2] = batch_semantic: unused by the reference
  const float* wv = (const float*)d_in[3];
  const float* Wu = (const float*)d_in[4];
  const float* bu = (const float*)d_in[5];
  const float* Wb = (const float*)d_in[6];
  const float* bb = (const float*)d_in[7];
  const float* Wt = (const float*)d_in[8];
  const float* bt = (const float*)d_in[9];
  float* out = (float*)d_out;

  // workspace layout (bytes), footprint 148,838,400 (offsets unchanged):
  //   P (fp8): [0, 23,101,440)           30080*768*1   (live: project..pool)
  //   W_bf:    [146,374,656, 146,866,176) 768*320*2    (dead after project)
  //   qvec:    [148,439,040, 148,832,256)
  //   qinv:    [148,832,256, 148,838,400)
  //   partial: [46,202,880, 52,690,944)  3072*528*4
  char* ws = (char*)d_ws;
  unsigned char* P      = (unsigned char*)(ws);
  unsigned short* W_bf  = (unsigned short*)(ws + 146374656);
  unsigned short* qvec  = (unsigned short*)(ws + 148439040);
  float* qinv           = (float*)(ws + 148832256);
  float* partial        = (float*)(ws + 46202880);

  k_convert<<<120, 256, 0, stream>>>(Wu, Wb, Wt, W_bf);
  k_project<<<1440, 256, 0, stream>>>(wv, W_bf, P);
  k_qvec<<<96, 256, 0, stream>>>(qtok, P, bu, bb, bt, qvec, qinv);
  k_pool<<<32 * 96, 256, 0, stream>>>(dtok, P, bu, bb, bt, qvec, qinv, partial);
  k_finale<<<198, 256, 0, stream>>>(partial, out);
}

// Round 15
// 189.771 us; speedup vs baseline: 1.0272x; 1.0272x over previous
//
#include <hip/hip_runtime.h>
#include <stdint.h>

// CONV-KNRM fused pipeline for MI355X (gfx950). Round 29 = recombination:
//  - k_pool: EXACT R26 structure (single 12-load sched_barrier-pinned batch,
//    (256,3), 64 VGPR, 58.5us measured). R28's double-batch unroll regressed
//    (VGPR 88, occ 22%, ~118us): losing a resident block cost more than the
//    serial-batch latency it hid. Reverted.
//  - k_project: KEEP R28's v_cvt_pk_bf16_f32 A-convert. Ledger arithmetic:
//    R28 other-stages = 194.9-118 = ~77us vs R26's 179.4-59 = ~120us ->
//    the cvt_pk change cut k_project ~44us (it was VALU-convert-bound).
// B=32, Q=16, D=4096, V=30000, C=128, EM=300, NBINS=11.

typedef short short8 __attribute__((ext_vector_type(8)));
typedef unsigned short ushort8 __attribute__((ext_vector_type(8)));
typedef float floatx4 __attribute__((ext_vector_type(4)));
typedef float floatx2 __attribute__((ext_vector_type(2)));

#define NB_V 30000

__device__ __forceinline__ unsigned short f32_bf16(float f) {
  union { float f; uint32_t u; } v; v.f = f;
  return (unsigned short)((v.u + 0x7FFFu + ((v.u >> 16) & 1u)) >> 16);
}
__device__ __forceinline__ float bits_f32(uint32_t u) {
  union { uint32_t u; float f; } v; v.u = u; return v.f;
}

// HW packed f32x2 -> bf16x2 (RNE; lo16=bf16(a), hi16=bf16(b))
__device__ __forceinline__ uint32_t cvt_pk_bf16(float a, float b) {
  uint32_t r;
  asm("v_cvt_pk_bf16_f32 %0, %1, %2" : "=v"(r) : "v"(a), "v"(b));
  return r;
}

// ---- fp8 e4m3 (OCP on gfx950) HW conversions ----
__device__ __forceinline__ floatx2 fp8x2_lo(uint32_t w) {
  return __builtin_amdgcn_cvt_pk_f32_fp8(w, false);   // bytes 0,1
}
__device__ __forceinline__ floatx2 fp8x2_hi(uint32_t w) {
  return __builtin_amdgcn_cvt_pk_f32_fp8(w, true);    // bytes 2,3
}
__device__ __forceinline__ unsigned char f32_fp8(float f) {
  return (unsigned char)(__builtin_amdgcn_cvt_pk_fp8_f32(f, f, 0, false) & 0xFF);
}

// lgkmcnt-only barrier: orders LDS reads/writes across waves without
// draining vmcnt (global stores / prefetched loads stay in flight).
__device__ __forceinline__ void barrier_lds() {
  asm volatile("s_waitcnt lgkmcnt(0)\n\ts_barrier" ::: "memory");
}

// ------------- W -> bf16 (768x320, zero-padded), tiny -------------
__global__ __launch_bounds__(256) void k_convert(
    const float* __restrict__ Wu, const float* __restrict__ Wb,
    const float* __restrict__ Wt,
    unsigned short* __restrict__ W_bf) {
  int u = blockIdx.x * 256 + threadIdx.x;
  if (u >= 768 * 40) return;
  int chg = u / 40, kc = u % 40;
  int seg = chg >> 7, ch = chg & 127;
  const float* Wsrc; int kw, jj;
  if (seg == 0)      { Wsrc = Wu; kw = 1; jj = 0; }
  else if (seg <= 2) { Wsrc = Wb; kw = 2; jj = seg - 1; }
  else               { Wsrc = Wt; kw = 3; jj = seg - 3; }
  const float* src = Wsrc + ((size_t)ch * kw + jj) * 300;
  int k0 = kc * 8;
  ushort8 o;
#pragma unroll
  for (int e = 0; e < 8; e++)
    o[e] = (k0 + e < 300) ? f32_bf16(src[k0 + e]) : (unsigned short)0;
  *(ushort8*)(W_bf + (size_t)chg * 320 + k0) = o;
}

// ---------------- Stage A: vocab projection GEMM ----------------
// grid = 1440 (240 mb-slots x 6 segs, mb>=235 idle). XCD-colocate:
// l=(bid%8)*180+bid/8. A read from wv f32 + HW cvt_pk_bf16 round (RNE,
// bit-identical to scalar magic; ~44us saver vs scalar per R28 ledger).
// 128 rows x 128 cols, K=320. 4 quarter-phases of 32 cols;
// LDS 32ch x 328 = 20,992B. Output P is fp8 e4m3.
__global__ __launch_bounds__(256) void k_project(
    const float* __restrict__ wv,
    const unsigned short* __restrict__ W_bf,
    unsigned char* __restrict__ P) {
  __shared__ __align__(16) unsigned short wlds[32 * 328];   // 20,992 B
  int tid = threadIdx.x;
  int p = blockIdx.x;
  int l = (p & 7) * 180 + (p >> 3);      // bijective 0..1439
  int mb = l / 6, seg = l - mb * 6;
  if (mb >= 235) return;
  int wave = tid >> 6, lane = tid & 63;
  int li = lane & 15, quad = lane >> 4;
  int rows0 = mb * 128 + wave * 32;

  // A-fragment register cache from f32 wv: both 16-row tiles, 10 K-steps.
  // K-tail clamp at 296: K=296..299 are valid; dup slots hit W zero-pad.
  short8 af[2][10];
  {
    int r0 = rows0 + li, r1 = rows0 + 16 + li;
    const float* a0 = wv + (size_t)(r0 < NB_V ? r0 : NB_V - 1) * 300;
    const float* a1 = wv + (size_t)(r1 < NB_V ? r1 : NB_V - 1) * 300;
#pragma unroll
    for (int ks = 0; ks < 10; ks++) {
      int k0 = ks * 32 + quad * 8;
      int ka = k0 > 296 ? 296 : k0;          // float4-aligned, in-bounds
      int kb = k0 + 4 > 296 ? 296 : k0 + 4;
      float4 x0 = *(const float4*)(a0 + ka);
      float4 x1 = *(const float4*)(a0 + kb);
      float4 y0 = *(const float4*)(a1 + ka);
      float4 y1 = *(const float4*)(a1 + kb);
      union { uint32_t u[4]; short8 s; } c0, c1;
      c0.u[0] = cvt_pk_bf16(x0.x, x0.y); c0.u[1] = cvt_pk_bf16(x0.z, x0.w);
      c0.u[2] = cvt_pk_bf16(x1.x, x1.y); c0.u[3] = cvt_pk_bf16(x1.z, x1.w);
      c1.u[0] = cvt_pk_bf16(y0.x, y0.y); c1.u[1] = cvt_pk_bf16(y0.z, y0.w);
      c1.u[2] = cvt_pk_bf16(y1.x, y1.y); c1.u[3] = cvt_pk_bf16(y1.z, y1.w);
      af[0][ks] = c0.s;
      af[1][ks] = c1.s;
    }
  }
  const unsigned short* wseg = W_bf + (size_t)seg * 128 * 320;

  for (int h = 0; h < 4; h++) {
    if (h) barrier_lds();   // prev quarter's ds_reads done before restage
    {  // stage 32 channels x 320 K from W_bf (uint4; dest row = 41 chunks)
#pragma unroll
      for (int i = 0; i < 5; i++) {
        int idx = i * 256 + tid;        // source chunk 0..1279
        int ch = idx / 40, kc = idx - ch * 40;
        uint4 v = *(const uint4*)(wseg + (size_t)(h * 32 + ch) * 320 + kc * 8);
        *(uint4*)(wlds + (ch * 41 + kc) * 8) = v;
      }
    }
    barrier_lds();

    floatx4 acc[2][2];
#pragma unroll
    for (int rt = 0; rt < 2; rt++)
#pragma unroll
      for (int ct = 0; ct < 2; ct++) acc[rt][ct] = (floatx4){0.f, 0.f, 0.f, 0.f};

#pragma unroll
    for (int ks = 0; ks < 10; ks++) {
      int ck = ks * 32 + quad * 8;
#pragma unroll
      for (int ct = 0; ct < 2; ct++) {
        short8 bf = *(const short8*)&wlds[(ct * 16 + li) * 328 + ck];
        acc[0][ct] = __builtin_amdgcn_mfma_f32_16x16x32_bf16(af[0][ks], bf, acc[0][ct], 0, 0, 0);
        acc[1][ct] = __builtin_amdgcn_mfma_f32_16x16x32_bf16(af[1][ks], bf, acc[1][ct], 0, 0, 0);
      }
    }
#pragma unroll
    for (int rt = 0; rt < 2; rt++)
#pragma unroll
      for (int ct = 0; ct < 2; ct++)
#pragma unroll
        for (int r = 0; r < 4; r++) {
          int row = rows0 + rt * 16 + quad * 4 + r;   // < 30080, P padded
          P[(size_t)row * 768 + seg * 128 + h * 32 + ct * 16 + li] =
              f32_fp8(acc[rt][ct][r]);
        }
  }
}

// ---------------- query n-gram vectors (tiny: 384 waves) ----------------
template <int KK>
__device__ __forceinline__ void build_qvec4(
    int b, int type, int l0,
    const int* __restrict__ tokens, const unsigned char* __restrict__ P,
    const float* __restrict__ bias,
    unsigned short* __restrict__ vec, float* __restrict__ inv, int lane) {
  const int segBase[3] = {0, 128, 384};
  int sub = lane >> 4, li = lane & 15;
  int l = l0 + sub;
  size_t row = (size_t)(b * 3 + type) * 16 + l;
  uint4 o = make_uint4(0u, 0u, 0u, 0u);
  float invv = 0.0f;
  if (l + KK <= 16) {
    float v[8];
    {
      float4 b0 = *(const float4*)(bias + li * 8);
      float4 b1 = *(const float4*)(bias + li * 8 + 4);
      v[0] = b0.x; v[1] = b0.y; v[2] = b0.z; v[3] = b0.w;
      v[4] = b1.x; v[5] = b1.y; v[6] = b1.z; v[7] = b1.w;
    }
    const int* tk = tokens + (size_t)b * 16 + l;
    const unsigned char* pb = P + segBase[type] + li * 8;
#pragma unroll
    for (int j = 0; j < KK; j++) {
      uint2 pp = *(const uint2*)(pb + (size_t)tk[j] * 768 + j * 128);
      floatx2 f0 = fp8x2_lo(pp.x), f1 = fp8x2_hi(pp.x);
      floatx2 f2 = fp8x2_lo(pp.y), f3 = fp8x2_hi(pp.y);
      v[0] += f0.x; v[1] += f0.y; v[2] += f1.x; v[3] += f1.y;
      v[4] += f2.x; v[5] += f2.y; v[6] += f3.x; v[7] += f3.y;
    }
    uint32_t w[4];
    float s = 0.0f;
#pragma unroll
    for (int e = 0; e < 4; e++) {
      float f0 = fmaxf(v[2 * e], 0.0f) + 1e-9f;
      float f1 = fmaxf(v[2 * e + 1], 0.0f) + 1e-9f;
      uint32_t wd = cvt_pk_bf16(f0, f1);   // lo=bf16(f0), hi=bf16(f1)
      w[e] = wd;
      float g0 = bits_f32(wd << 16);
      float g1 = bits_f32(wd & 0xFFFF0000u);
      s = fmaf(g0, g0, fmaf(g1, g1, s));
    }
#pragma unroll
    for (int off = 1; off < 16; off <<= 1) s += __shfl_xor(s, off);
    invv = rsqrtf(s);
    o = make_uint4(w[0], w[1], w[2], w[3]);
  }
  *(uint4*)(vec + row * 128 + li * 8) = o;
  if (li == 0) inv[row] = invv;
}

__global__ __launch_bounds__(256) void k_qvec(
    const int* __restrict__ qtok, const unsigned char* __restrict__ P,
    const float* __restrict__ bu, const float* __restrict__ bb,
    const float* __restrict__ bt,
    unsigned short* __restrict__ qvec, float* __restrict__ qinv) {
  int wid = blockIdx.x * 4 + (threadIdx.x >> 6);  // 0..383
  int lane = threadIdx.x & 63;
  int b = wid / 12;
  int rem = wid % 12;
  int type = rem / 4, l0 = (rem % 4) * 4;
  if (type == 0)      build_qvec4<1>(b, 0, l0, qtok, P, bu, qvec, qinv, lane);
  else if (type == 1) build_qvec4<2>(b, 1, l0, qtok, P, bb, qvec, qinv, lane);
  else                build_qvec4<3>(b, 2, l0, qtok, P, bt, qvec, qinv, lane);
}

// ------- Stage C: fused doc-build-in-registers + sim MFMA + pooling -------
// LPT grid: bid/1024 -> dt=2,1,0; b = (bid%1024)/32, chunk = bid%32.
// pacc ALIASES qlds. Batched fp8 gather pinned by sched_barrier(0).
// Packed-f32 decode accumulate, HW cvt_pk_bf16 pack, 5x-float2 bin loop.
// (R26 structure exactly; R28's double-batch unroll reverted.)
template <int KK>
__device__ __forceinline__ void pool_body(
    int b, int chunk, const int* __restrict__ dtok,
    const unsigned char* __restrict__ P, const float* __restrict__ bias,
    const unsigned short* qlds, const float* qil, float* pacc,
    float* __restrict__ pout, int tid) {
  constexpr int dt = KK - 1;
  constexpr int segB = (dt == 0) ? 0 : (dt == 1) ? 128 : 384;
  const int wave = tid >> 6, lane = tid & 63;
  const int li = lane & 15, quad = lane >> 4;
  const int validD = 4096 - dt;

  float acc0[3];                 // bin 0 (sigma=0.001)
  floatx2 acc2[3][5];            // bins (1,2),(3,4),(5,6),(7,8),(9,10)
#pragma unroll
  for (int qt = 0; qt < 3; qt++) {
    acc0[qt] = 0.f;
#pragma unroll
    for (int p = 0; p < 5; p++) acc2[qt][p] = (floatx2){0.f, 0.f};
  }

  for (int grp = wave; grp < 8; grp += 4) {
    int d0 = chunk * 128 + grp * 16;
    int mydoc = d0 + li;                 // this lane builds doc `mydoc`
    bool ok = (mydoc + KK <= 4096);
    int tox[KK];
#pragma unroll
    for (int j = 0; j < KK; j++) {
      int ti = mydoc + j; if (ti > 4095) ti = 4095;   // clamp: value unused if !ok
      tox[j] = dtok[(size_t)b * 4096 + ti];
    }
    // ---- batched gather: ALL KK*4 uint2 loads in flight before unpack ----
    uint2 pp[KK][4];
#pragma unroll
    for (int j = 0; j < KK; j++) {
      const unsigned char* rp = P + (size_t)tox[j] * 768 + segB + j * 128 + quad * 8;
#pragma unroll
      for (int sl = 0; sl < 4; sl++)
        pp[j][sl] = *(const uint2*)(rp + sl * 32);
    }
    // Pin the batch: nothing (esp. the unpack below) may be scheduled above
    // this point, so all KK*4 loads stay issued back-to-back (MLP ~12/wave).
    __builtin_amdgcn_sched_barrier(0);
    float sq = 0.f;
    short8 af[4];
#pragma unroll
    for (int sl = 0; sl < 4; sl++) {
      int co = sl * 32 + quad * 8;       // channel (byte) offset within segment
      floatx2 v2[4];
      {
        const floatx2* b2 = (const floatx2*)(bias + co);
        v2[0] = b2[0]; v2[1] = b2[1]; v2[2] = b2[2]; v2[3] = b2[3];
      }
#pragma unroll
      for (int j = 0; j < KK; j++) {
        uint2 pq = pp[j][sl];
        v2[0] += fp8x2_lo(pq.x); v2[1] += fp8x2_hi(pq.x);
        v2[2] += fp8x2_lo(pq.y); v2[3] += fp8x2_hi(pq.y);
      }
      union { uint32_t u[4]; short8 s8; } pk;
#pragma unroll
      for (int e = 0; e < 4; e++) {
        float f0 = fmaxf(v2[e].x, 0.0f) + 1e-9f;
        float f1 = fmaxf(v2[e].y, 0.0f) + 1e-9f;
        uint32_t wd = cvt_pk_bf16(f0, f1);
        pk.u[e] = wd;
        float g0 = bits_f32(wd << 16);
        float g1 = bits_f32(wd & 0xFFFF0000u);
        sq = fmaf(g0, g0, fmaf(g1, g1, sq));
      }
      af[sl] = pk.s8;   // garbage rows are masked by validD below
    }
    sq += __shfl_xor(sq, 16);           // reduce over quads (same doc)
    sq += __shfl_xor(sq, 32);
    float invd = ok ? rsqrtf(sq) : 0.0f;
    float iv[4];
#pragma unroll
    for (int r = 0; r < 4; r++) iv[r] = __shfl(invd, quad * 4 + r);

#pragma unroll
    for (int qt = 0; qt < 3; qt++) {
      floatx4 sim = (floatx4){0.f, 0.f, 0.f, 0.f};
      const unsigned short* qb = qlds + (qt * 16 + li) * 136 + quad * 8;
      sim = __builtin_amdgcn_mfma_f32_16x16x32_bf16(af[0], *(const short8*)(qb), sim, 0, 0, 0);
      sim = __builtin_amdgcn_mfma_f32_16x16x32_bf16(af[1], *(const short8*)(qb + 32), sim, 0, 0, 0);
      sim = __builtin_amdgcn_mfma_f32_16x16x32_bf16(af[2], *(const short8*)(qb + 64), sim, 0, 0, 0);
      sim = __builtin_amdgcn_mfma_f32_16x16x32_bf16(af[3], *(const short8*)(qb + 96), sim, 0, 0, 0);
      float invq = qil[qt * 16 + li];
#pragma unroll
      for (int r = 0; r < 4; r++) {
        if (d0 + quad * 4 + r < validD) {
          float s = sim[r] * (invq * iv[r]);
          // bin 0 (sigma=0.001): exp underflows to 0 unless s ~ 1
          if (s > 0.9868f) {
            float t0 = s - 1.0f;
            acc0[qt] += __expf(t0 * t0 * -500000.0f);
          }
          // bins 1..10 packed: F=(f_i, f_{i+1}), M=(v^2c, v^2c^3), M*=c^4
          float y = s - 0.9f;
          float f = __expf(y * y * -50.0f);
          float v = __expf(fmaf(y, -20.0f, -2.0f));
          floatx2 F; F.x = f; F.y = f * v;
          float vv = v * v;
          floatx2 M; M.x = vv * 0.018315639f;        // v^2 e^-4
          M.y = M.x * 3.3546263e-4f;                 // v^2 e^-12
          const floatx2 C4 = {1.1253517e-7f, 1.1253517e-7f};  // e^-16
#pragma unroll
          for (int pi = 0; pi < 5; pi++) {
            acc2[qt][pi] += F;
            F *= M;
            M *= C4;
          }
        }
      }
    }
  }
  // pacc aliases qlds: ALL waves must finish their MFMA qlds reads before
  // any wave overwrites the buffer with partial accumulators.
  __syncthreads();
#pragma unroll
  for (int qt = 0; qt < 3; qt++) {
    {
      float v = acc0[qt];
      v += __shfl_xor(v, 16);
      v += __shfl_xor(v, 32);
      if (lane < 16) pacc[wave * 528 + (qt * 16 + lane) * 11 + 0] = v;
    }
#pragma unroll
    for (int p = 0; p < 5; p++) {
      float vx = acc2[qt][p].x, vy = acc2[qt][p].y;
      vx += __shfl_xor(vx, 16); vx += __shfl_xor(vx, 32);
      vy += __shfl_xor(vy, 16); vy += __shfl_xor(vy, 32);
      if (lane < 16) {
        pacc[wave * 528 + (qt * 16 + lane) * 11 + 2 * p + 1] = vx;
        pacc[wave * 528 + (qt * 16 + lane) * 11 + 2 * p + 2] = vy;
      }
    }
  }
  __syncthreads();
  for (int idx = tid; idx < 528; idx += 256)
    pout[idx] = pacc[idx] + pacc[528 + idx] + pacc[1056 + idx] + pacc[1584 + idx];
}

__global__ __launch_bounds__(256, 3) void k_pool(
    const int* __restrict__ dtok,
    const unsigned char* __restrict__ P,
    const float* __restrict__ bu, const float* __restrict__ bb,
    const float* __restrict__ bt,
    const unsigned short* __restrict__ qvec, const float* __restrict__ qinv,
    float* __restrict__ partial) {
  // qlds (13,056 B) doubles as pacc (8,448 B) after the main loop.
  __shared__ __align__(16) unsigned short qlds[48 * 136];   // 13,056 B
  __shared__ float qil[48];
  int bid = blockIdx.x;
  // LPT: heavy dt=2 first (bid 0..1023), then dt=1, then dt=0.
  int dt = 2 - (bid >> 10);
  int r = bid & 1023;
  int b = r >> 5, chunk = r & 31;
  int tid = threadIdx.x;
  for (int idx = tid; idx < 48 * 32; idx += 256) {
    int row = idx >> 5, kq = (idx & 31) * 4;
    *(uint2*)&qlds[row * 136 + kq] =
        *(const uint2*)(qvec + ((size_t)b * 48 + row) * 128 + kq);
  }
  if (tid < 48) qil[tid] = qinv[b * 48 + tid];
  __syncthreads();
  float* pacc = (float*)qlds;   // alias: safe via barrier in pool_body
  float* pout = partial + ((size_t)((b * 3 + dt) * 32) + chunk) * 528;
  if (dt == 0)      pool_body<1>(b, chunk, dtok, P, bu, qlds, qil, pacc, pout, tid);
  else if (dt == 1) pool_body<2>(b, chunk, dtok, P, bb, qlds, qil, pacc, pout, tid);
  else              pool_body<3>(b, chunk, dtok, P, bt, qlds, qil, pacc, pout, tid);
}

// ------- fused chunk-reduce + log + query-sum epilogue (one dispatch) -------
__global__ __launch_bounds__(256) void k_finale(const float* __restrict__ partial,
                                                float* __restrict__ out) {
  int idx = blockIdx.x * 256 + threadIdx.x;   // 50688 total
  if (idx >= 32 * 3 * 3 * 11 * 16) return;
  int q = idx & 15;
  int g = idx >> 4;                 // (b,qt,dt,bin), bin fastest
  int bin = g % 11; g /= 11;
  int dt = g % 3; g /= 3;
  int qt = g % 3; int b = g / 3;
  const float* p = partial + ((size_t)(b * 3 + dt) * 32) * 528 + (qt * 16 + q) * 11 + bin;
  float s = 0.f;
#pragma unroll
  for (int c = 0; c < 32; c++) s += p[c * 528];
  float t = (q < 16 - qt) ? 0.01f * logf(fmaxf(s, 1e-10f)) : 0.0f;
#pragma unroll
  for (int off = 1; off < 16; off <<= 1) t += __shfl_xor(t, off);
  if (q == 0) {
    const int p_of[3][3] = {{0, 2, 1}, {3, 5, 6}, {4, 7, 8}};
    out[b * 99 + p_of[qt][dt] * 11 + bin] = t;
  }
}

extern "C" void kernel_launch(void* const* d_in, const int* in_sizes, int n_in,
                              void* d_out, int out_size, void* d_ws, size_t ws_size,
                              hipStream_t stream) {
  const int* qtok = (const int*)d_in[0];
  const int* dtok = (const int*)d_in[1];
  // d_in[2] = batch_semantic: unused by the reference
  const float* wv = (const float*)d_in[3];
  const float* Wu = (const float*)d_in[4];
  const float* bu = (const float*)d_in[5];
  const float* Wb = (const float*)d_in[6];
  const float* bb = (const float*)d_in[7];
  const float* Wt = (const float*)d_in[8];
  const float* bt = (const float*)d_in[9];
  float* out = (float*)d_out;

  // workspace layout (bytes), footprint 148,838,400 (offsets unchanged):
  //   P (fp8): [0, 23,101,440)           30080*768*1   (live: project..pool)
  //   W_bf:    [146,374,656, 146,866,176) 768*320*2    (dead after project)
  //   qvec:    [148,439,040, 148,832,256)
  //   qinv:    [148,832,256, 148,838,400)
  //   partial: [46,202,880, 52,690,944)  3072*528*4
  char* ws = (char*)d_ws;
  unsigned char* P      = (unsigned char*)(ws);
  unsigned short* W_bf  = (unsigned short*)(ws + 146374656);
  unsigned short* qvec  = (unsigned short*)(ws + 148439040);
  float* qinv           = (float*)(ws + 148832256);
  float* partial        = (float*)(ws + 46202880);

  k_convert<<<120, 256, 0, stream>>>(Wu, Wb, Wt, W_bf);
  k_project<<<1440, 256, 0, stream>>>(wv, W_bf, P);
  k_qvec<<<96, 256, 0, stream>>>(qtok, P, bu, bb, bt, qvec, qinv);
  k_pool<<<32 * 96, 256, 0, stream>>>(dtok, P, bu, bb, bt, qvec, qinv, partial);
  k_finale<<<198, 256, 0, stream>>>(partial, out);
}

// Round 16
// 173.093 us; speedup vs baseline: 1.1262x; 1.0963x over previous
//
#include <hip/hip_runtime.h>
#include <stdint.h>

// CONV-KNRM fused pipeline for MI355X (gfx950). Round 30:
//  - k_project A-convert REVERTED to scalar magic (exact R26). R29's direct
//    A/B proved the inline-asm cvt_pk A-convert costs +10us (asm blocks the
//    prologue load/ALU interleave; matches m240). R28's "other=77us" ledger
//    was cross-measurement garbage (profiled k_pool minus timed total).
//  - NEW: P intra-segment layout permuted to quad-major: channel
//    c = sl*32+q*8+e stored at pos = q*32+sl*8+e. Each k_pool thread's
//    4x8B strided gathers per tap become ONE contiguous 32B run -> 2x uint4
//    loads (12->6 VMEM ops per batch, same bytes, bit-identical numerics).
//    k_project epilogue + k_qvec recompute offsets (free).
// B=32, Q=16, D=4096, V=30000, C=128, EM=300, NBINS=11.

typedef short short8 __attribute__((ext_vector_type(8)));
typedef unsigned short ushort8 __attribute__((ext_vector_type(8)));
typedef float floatx4 __attribute__((ext_vector_type(4)));
typedef float floatx2 __attribute__((ext_vector_type(2)));

#define NB_V 30000

__device__ __forceinline__ unsigned short f32_bf16(float f) {
  union { float f; uint32_t u; } v; v.f = f;
  return (unsigned short)((v.u + 0x7FFFu + ((v.u >> 16) & 1u)) >> 16);
}
__device__ __forceinline__ float bits_f32(uint32_t u) {
  union { uint32_t u; float f; } v; v.u = u; return v.f;
}

// HW packed f32x2 -> bf16x2 (RNE; lo16=bf16(a), hi16=bf16(b)).
// Used ONLY in k_pool/k_qvec hot loops (behind the pinned gather batch);
// R29 proved it hurts in k_project's prologue.
__device__ __forceinline__ uint32_t cvt_pk_bf16(float a, float b) {
  uint32_t r;
  asm("v_cvt_pk_bf16_f32 %0, %1, %2" : "=v"(r) : "v"(a), "v"(b));
  return r;
}

// ---- fp8 e4m3 (OCP on gfx950) HW conversions ----
__device__ __forceinline__ floatx2 fp8x2_lo(uint32_t w) {
  return __builtin_amdgcn_cvt_pk_f32_fp8(w, false);   // bytes 0,1
}
__device__ __forceinline__ floatx2 fp8x2_hi(uint32_t w) {
  return __builtin_amdgcn_cvt_pk_f32_fp8(w, true);    // bytes 2,3
}
__device__ __forceinline__ unsigned char f32_fp8(float f) {
  return (unsigned char)(__builtin_amdgcn_cvt_pk_fp8_f32(f, f, 0, false) & 0xFF);
}

// lgkmcnt-only barrier: orders LDS reads/writes across waves without
// draining vmcnt (global stores / prefetched loads stay in flight).
__device__ __forceinline__ void barrier_lds() {
  asm volatile("s_waitcnt lgkmcnt(0)\n\ts_barrier" ::: "memory");
}

// ------------- W -> bf16 (768x320, zero-padded), tiny -------------
__global__ __launch_bounds__(256) void k_convert(
    const float* __restrict__ Wu, const float* __restrict__ Wb,
    const float* __restrict__ Wt,
    unsigned short* __restrict__ W_bf) {
  int u = blockIdx.x * 256 + threadIdx.x;
  if (u >= 768 * 40) return;
  int chg = u / 40, kc = u % 40;
  int seg = chg >> 7, ch = chg & 127;
  const float* Wsrc; int kw, jj;
  if (seg == 0)      { Wsrc = Wu; kw = 1; jj = 0; }
  else if (seg <= 2) { Wsrc = Wb; kw = 2; jj = seg - 1; }
  else               { Wsrc = Wt; kw = 3; jj = seg - 3; }
  const float* src = Wsrc + ((size_t)ch * kw + jj) * 300;
  int k0 = kc * 8;
  ushort8 o;
#pragma unroll
  for (int e = 0; e < 8; e++)
    o[e] = (k0 + e < 300) ? f32_bf16(src[k0 + e]) : (unsigned short)0;
  *(ushort8*)(W_bf + (size_t)chg * 320 + k0) = o;
}

// ---------------- Stage A: vocab projection GEMM ----------------
// grid = 1440 (240 mb-slots x 6 segs, mb>=235 idle). XCD-colocate:
// l=(bid%8)*180+bid/8. A read from wv f32 + scalar-magic bf16 round (R26
// form; asm cvt_pk here costs +10us, R29). 128 rows x 128 cols, K=320.
// 4 quarter-phases of 32 cols; LDS 32ch x 328 = 20,992B. Output P is fp8
// e4m3 in QUAD-MAJOR segment layout: channel c=sl*32+q*8+e at q*32+sl*8+e.
__global__ __launch_bounds__(256) void k_project(
    const float* __restrict__ wv,
    const unsigned short* __restrict__ W_bf,
    unsigned char* __restrict__ P) {
  __shared__ __align__(16) unsigned short wlds[32 * 328];   // 20,992 B
  int tid = threadIdx.x;
  int p = blockIdx.x;
  int l = (p & 7) * 180 + (p >> 3);      // bijective 0..1439
  int mb = l / 6, seg = l - mb * 6;
  if (mb >= 235) return;
  int wave = tid >> 6, lane = tid & 63;
  int li = lane & 15, quad = lane >> 4;
  int rows0 = mb * 128 + wave * 32;

  // A-fragment register cache from f32 wv: both 16-row tiles, 10 K-steps.
  // K-tail clamp at 296: K=296..299 are valid; dup slots hit W zero-pad.
  short8 af[2][10];
  {
    int r0 = rows0 + li, r1 = rows0 + 16 + li;
    const float* a0 = wv + (size_t)(r0 < NB_V ? r0 : NB_V - 1) * 300;
    const float* a1 = wv + (size_t)(r1 < NB_V ? r1 : NB_V - 1) * 300;
#pragma unroll
    for (int ks = 0; ks < 10; ks++) {
      int k0 = ks * 32 + quad * 8;
      int ka = k0 > 296 ? 296 : k0;          // float4-aligned, in-bounds
      int kb = k0 + 4 > 296 ? 296 : k0 + 4;
      float4 x0 = *(const float4*)(a0 + ka);
      float4 x1 = *(const float4*)(a0 + kb);
      float4 y0 = *(const float4*)(a1 + ka);
      float4 y1 = *(const float4*)(a1 + kb);
      short8 s0, s1;
      s0[0] = (short)f32_bf16(x0.x); s0[1] = (short)f32_bf16(x0.y);
      s0[2] = (short)f32_bf16(x0.z); s0[3] = (short)f32_bf16(x0.w);
      s0[4] = (short)f32_bf16(x1.x); s0[5] = (short)f32_bf16(x1.y);
      s0[6] = (short)f32_bf16(x1.z); s0[7] = (short)f32_bf16(x1.w);
      s1[0] = (short)f32_bf16(y0.x); s1[1] = (short)f32_bf16(y0.y);
      s1[2] = (short)f32_bf16(y0.z); s1[3] = (short)f32_bf16(y0.w);
      s1[4] = (short)f32_bf16(y1.x); s1[5] = (short)f32_bf16(y1.y);
      s1[6] = (short)f32_bf16(y1.z); s1[7] = (short)f32_bf16(y1.w);
      af[0][ks] = s0;
      af[1][ks] = s1;
    }
  }
  const unsigned short* wseg = W_bf + (size_t)seg * 128 * 320;

  for (int h = 0; h < 4; h++) {
    if (h) barrier_lds();   // prev quarter's ds_reads done before restage
    {  // stage 32 channels x 320 K from W_bf (uint4; dest row = 41 chunks)
#pragma unroll
      for (int i = 0; i < 5; i++) {
        int idx = i * 256 + tid;        // source chunk 0..1279
        int ch = idx / 40, kc = idx - ch * 40;
        uint4 v = *(const uint4*)(wseg + (size_t)(h * 32 + ch) * 320 + kc * 8);
        *(uint4*)(wlds + (ch * 41 + kc) * 8) = v;
      }
    }
    barrier_lds();

    floatx4 acc[2][2];
#pragma unroll
    for (int rt = 0; rt < 2; rt++)
#pragma unroll
      for (int ct = 0; ct < 2; ct++) acc[rt][ct] = (floatx4){0.f, 0.f, 0.f, 0.f};

#pragma unroll
    for (int ks = 0; ks < 10; ks++) {
      int ck = ks * 32 + quad * 8;
#pragma unroll
      for (int ct = 0; ct < 2; ct++) {
        short8 bf = *(const short8*)&wlds[(ct * 16 + li) * 328 + ck];
        acc[0][ct] = __builtin_amdgcn_mfma_f32_16x16x32_bf16(af[0][ks], bf, acc[0][ct], 0, 0, 0);
        acc[1][ct] = __builtin_amdgcn_mfma_f32_16x16x32_bf16(af[1][ks], bf, acc[1][ct], 0, 0, 0);
      }
    }
    // epilogue: channel within segment c = h*32 + ct*16 + li (sl=h, cc=ct*16+li)
    // quad-major pos = (cc>>3)*32 + h*8 + (cc&7)
#pragma unroll
    for (int rt = 0; rt < 2; rt++)
#pragma unroll
      for (int ct = 0; ct < 2; ct++) {
        int cc = ct * 16 + li;
        int pos = (cc >> 3) * 32 + h * 8 + (cc & 7);
#pragma unroll
        for (int r = 0; r < 4; r++) {
          int row = rows0 + rt * 16 + quad * 4 + r;   // < 30080, P padded
          P[(size_t)row * 768 + seg * 128 + pos] = f32_fp8(acc[rt][ct][r]);
        }
      }
  }
}

// ---------------- query n-gram vectors (tiny: 384 waves) ----------------
// Reads channels c = li*8..li*8+8 -> quad-major pos = (li&3)*32+(li>>2)*8.
template <int KK>
__device__ __forceinline__ void build_qvec4(
    int b, int type, int l0,
    const int* __restrict__ tokens, const unsigned char* __restrict__ P,
    const float* __restrict__ bias,
    unsigned short* __restrict__ vec, float* __restrict__ inv, int lane) {
  const int segBase[3] = {0, 128, 384};
  int sub = lane >> 4, li = lane & 15;
  int l = l0 + sub;
  size_t row = (size_t)(b * 3 + type) * 16 + l;
  uint4 o = make_uint4(0u, 0u, 0u, 0u);
  float invv = 0.0f;
  if (l + KK <= 16) {
    float v[8];
    {
      float4 b0 = *(const float4*)(bias + li * 8);
      float4 b1 = *(const float4*)(bias + li * 8 + 4);
      v[0] = b0.x; v[1] = b0.y; v[2] = b0.z; v[3] = b0.w;
      v[4] = b1.x; v[5] = b1.y; v[6] = b1.z; v[7] = b1.w;
    }
    const int* tk = tokens + (size_t)b * 16 + l;
    const unsigned char* pb = P + segBase[type] + (li & 3) * 32 + (li >> 2) * 8;
#pragma unroll
    for (int j = 0; j < KK; j++) {
      uint2 pp = *(const uint2*)(pb + (size_t)tk[j] * 768 + j * 128);
      floatx2 f0 = fp8x2_lo(pp.x), f1 = fp8x2_hi(pp.x);
      floatx2 f2 = fp8x2_lo(pp.y), f3 = fp8x2_hi(pp.y);
      v[0] += f0.x; v[1] += f0.y; v[2] += f1.x; v[3] += f1.y;
      v[4] += f2.x; v[5] += f2.y; v[6] += f3.x; v[7] += f3.y;
    }
    uint32_t w[4];
    float s = 0.0f;
#pragma unroll
    for (int e = 0; e < 4; e++) {
      float f0 = fmaxf(v[2 * e], 0.0f) + 1e-9f;
      float f1 = fmaxf(v[2 * e + 1], 0.0f) + 1e-9f;
      uint32_t wd = cvt_pk_bf16(f0, f1);   // lo=bf16(f0), hi=bf16(f1)
      w[e] = wd;
      float g0 = bits_f32(wd << 16);
      float g1 = bits_f32(wd & 0xFFFF0000u);
      s = fmaf(g0, g0, fmaf(g1, g1, s));
    }
#pragma unroll
    for (int off = 1; off < 16; off <<= 1) s += __shfl_xor(s, off);
    invv = rsqrtf(s);
    o = make_uint4(w[0], w[1], w[2], w[3]);
  }
  *(uint4*)(vec + row * 128 + li * 8) = o;
  if (li == 0) inv[row] = invv;
}

__global__ __launch_bounds__(256) void k_qvec(
    const int* __restrict__ qtok, const unsigned char* __restrict__ P,
    const float* __restrict__ bu, const float* __restrict__ bb,
    const float* __restrict__ bt,
    unsigned short* __restrict__ qvec, float* __restrict__ qinv) {
  int wid = blockIdx.x * 4 + (threadIdx.x >> 6);  // 0..383
  int lane = threadIdx.x & 63;
  int b = wid / 12;
  int rem = wid % 12;
  int type = rem / 4, l0 = (rem % 4) * 4;
  if (type == 0)      build_qvec4<1>(b, 0, l0, qtok, P, bu, qvec, qinv, lane);
  else if (type == 1) build_qvec4<2>(b, 1, l0, qtok, P, bb, qvec, qinv, lane);
  else                build_qvec4<3>(b, 2, l0, qtok, P, bt, qvec, qinv, lane);
}

// ------- Stage C: fused doc-build-in-registers + sim MFMA + pooling -------
// LPT grid: bid/1024 -> dt=2,1,0; b = (bid%1024)/32, chunk = bid%32.
// pacc ALIASES qlds. Quad-major P: each thread's 4 sl-slices are ONE
// contiguous 32B run at quad*32 -> 2x uint4 per tap (6 loads/batch, was 12),
// sched_barrier-pinned. Packed-f32 unpack, cvt_pk_bf16, packed bins.
template <int KK>
__device__ __forceinline__ void pool_body(
    int b, int chunk, const int* __restrict__ dtok,
    const unsigned char* __restrict__ P, const float* __restrict__ bias,
    const unsigned short* qlds, const float* qil, float* pacc,
    float* __restrict__ pout, int tid) {
  constexpr int dt = KK - 1;
  constexpr int segB = (dt == 0) ? 0 : (dt == 1) ? 128 : 384;
  const int wave = tid >> 6, lane = tid & 63;
  const int li = lane & 15, quad = lane >> 4;
  const int validD = 4096 - dt;

  float acc0[3];                 // bin 0 (sigma=0.001)
  floatx2 acc2[3][5];            // bins (1,2),(3,4),(5,6),(7,8),(9,10)
#pragma unroll
  for (int qt = 0; qt < 3; qt++) {
    acc0[qt] = 0.f;
#pragma unroll
    for (int p = 0; p < 5; p++) acc2[qt][p] = (floatx2){0.f, 0.f};
  }

  for (int grp = wave; grp < 8; grp += 4) {
    int d0 = chunk * 128 + grp * 16;
    int mydoc = d0 + li;                 // this lane builds doc `mydoc`
    bool ok = (mydoc + KK <= 4096);
    int tox[KK];
#pragma unroll
    for (int j = 0; j < KK; j++) {
      int ti = mydoc + j; if (ti > 4095) ti = 4095;   // clamp: value unused if !ok
      tox[j] = dtok[(size_t)b * 4096 + ti];
    }
    // ---- batched gather: KK taps x 2 uint4 (32B contiguous per tap) ----
    uint4 ppa[KK], ppb[KK];
#pragma unroll
    for (int j = 0; j < KK; j++) {
      const unsigned char* rp = P + (size_t)tox[j] * 768 + segB + j * 128 + quad * 32;
      ppa[j] = *(const uint4*)(rp);
      ppb[j] = *(const uint4*)(rp + 16);
    }
    // Pin the batch: all loads issued back-to-back before any unpack.
    __builtin_amdgcn_sched_barrier(0);
    float sq = 0.f;
    short8 af[4];
#pragma unroll
    for (int sl = 0; sl < 4; sl++) {
      int co = sl * 32 + quad * 8;       // channel offset (bias is channel-space)
      floatx2 v2[4];
      {
        const floatx2* b2 = (const floatx2*)(bias + co);
        v2[0] = b2[0]; v2[1] = b2[1]; v2[2] = b2[2]; v2[3] = b2[3];
      }
#pragma unroll
      for (int j = 0; j < KK; j++) {
        uint32_t wa, wb;
        if (sl == 0)      { wa = ppa[j].x; wb = ppa[j].y; }
        else if (sl == 1) { wa = ppa[j].z; wb = ppa[j].w; }
        else if (sl == 2) { wa = ppb[j].x; wb = ppb[j].y; }
        else              { wa = ppb[j].z; wb = ppb[j].w; }
        v2[0] += fp8x2_lo(wa); v2[1] += fp8x2_hi(wa);
        v2[2] += fp8x2_lo(wb); v2[3] += fp8x2_hi(wb);
      }
      union { uint32_t u[4]; short8 s8; } pk;
#pragma unroll
      for (int e = 0; e < 4; e++) {
        float f0 = fmaxf(v2[e].x, 0.0f) + 1e-9f;
        float f1 = fmaxf(v2[e].y, 0.0f) + 1e-9f;
        uint32_t wd = cvt_pk_bf16(f0, f1);
        pk.u[e] = wd;
        float g0 = bits_f32(wd << 16);
        float g1 = bits_f32(wd & 0xFFFF0000u);
        sq = fmaf(g0, g0, fmaf(g1, g1, sq));
      }
      af[sl] = pk.s8;   // garbage rows are masked by validD below
    }
    sq += __shfl_xor(sq, 16);           // reduce over quads (same doc)
    sq += __shfl_xor(sq, 32);
    float invd = ok ? rsqrtf(sq) : 0.0f;
    float iv[4];
#pragma unroll
    for (int r = 0; r < 4; r++) iv[r] = __shfl(invd, quad * 4 + r);

#pragma unroll
    for (int qt = 0; qt < 3; qt++) {
      floatx4 sim = (floatx4){0.f, 0.f, 0.f, 0.f};
      const unsigned short* qb = qlds + (qt * 16 + li) * 136 + quad * 8;
      sim = __builtin_amdgcn_mfma_f32_16x16x32_bf16(af[0], *(const short8*)(qb), sim, 0, 0, 0);
      sim = __builtin_amdgcn_mfma_f32_16x16x32_bf16(af[1], *(const short8*)(qb + 32), sim, 0, 0, 0);
      sim = __builtin_amdgcn_mfma_f32_16x16x32_bf16(af[2], *(const short8*)(qb + 64), sim, 0, 0, 0);
      sim = __builtin_amdgcn_mfma_f32_16x16x32_bf16(af[3], *(const short8*)(qb + 96), sim, 0, 0, 0);
      float invq = qil[qt * 16 + li];
#pragma unroll
      for (int r = 0; r < 4; r++) {
        if (d0 + quad * 4 + r < validD) {
          float s = sim[r] * (invq * iv[r]);
          // bin 0 (sigma=0.001): exp underflows to 0 unless s ~ 1
          if (s > 0.9868f) {
            float t0 = s - 1.0f;
            acc0[qt] += __expf(t0 * t0 * -500000.0f);
          }
          // bins 1..10 packed: F=(f_i, f_{i+1}), M=(v^2c, v^2c^3), M*=c^4
          float y = s - 0.9f;
          float f = __expf(y * y * -50.0f);
          float v = __expf(fmaf(y, -20.0f, -2.0f));
          floatx2 F; F.x = f; F.y = f * v;
          float vv = v * v;
          floatx2 M; M.x = vv * 0.018315639f;        // v^2 e^-4
          M.y = M.x * 3.3546263e-4f;                 // v^2 e^-12
          const floatx2 C4 = {1.1253517e-7f, 1.1253517e-7f};  // e^-16
#pragma unroll
          for (int pi = 0; pi < 5; pi++) {
            acc2[qt][pi] += F;
            F *= M;
            M *= C4;
          }
        }
      }
    }
  }
  // pacc aliases qlds: ALL waves must finish their MFMA qlds reads before
  // any wave overwrites the buffer with partial accumulators.
  __syncthreads();
#pragma unroll
  for (int qt = 0; qt < 3; qt++) {
    {
      float v = acc0[qt];
      v += __shfl_xor(v, 16);
      v += __shfl_xor(v, 32);
      if (lane < 16) pacc[wave * 528 + (qt * 16 + lane) * 11 + 0] = v;
    }
#pragma unroll
    for (int p = 0; p < 5; p++) {
      float vx = acc2[qt][p].x, vy = acc2[qt][p].y;
      vx += __shfl_xor(vx, 16); vx += __shfl_xor(vx, 32);
      vy += __shfl_xor(vy, 16); vy += __shfl_xor(vy, 32);
      if (lane < 16) {
        pacc[wave * 528 + (qt * 16 + lane) * 11 + 2 * p + 1] = vx;
        pacc[wave * 528 + (qt * 16 + lane) * 11 + 2 * p + 2] = vy;
      }
    }
  }
  __syncthreads();
  for (int idx = tid; idx < 528; idx += 256)
    pout[idx] = pacc[idx] + pacc[528 + idx] + pacc[1056 + idx] + pacc[1584 + idx];
}

__global__ __launch_bounds__(256, 3) void k_pool(
    const int* __restrict__ dtok,
    const unsigned char* __restrict__ P,
    const float* __restrict__ bu, const float* __restrict__ bb,
    const float* __restrict__ bt,
    const unsigned short* __restrict__ qvec, const float* __restrict__ qinv,
    float* __restrict__ partial) {
  // qlds (13,056 B) doubles as pacc (8,448 B) after the main loop.
  __shared__ __align__(16) unsigned short qlds[48 * 136];   // 13,056 B
  __shared__ float qil[48];
  int bid = blockIdx.x;
  // LPT: heavy dt=2 first (bid 0..1023), then dt=1, then dt=0.
  int dt = 2 - (bid >> 10);
  int r = bid & 1023;
  int b = r >> 5, chunk = r & 31;
  int tid = threadIdx.x;
  for (int idx = tid; idx < 48 * 32; idx += 256) {
    int row = idx >> 5, kq = (idx & 31) * 4;
    *(uint2*)&qlds[row * 136 + kq] =
        *(const uint2*)(qvec + ((size_t)b * 48 + row) * 128 + kq);
  }
  if (tid < 48) qil[tid] = qinv[b * 48 + tid];
  __syncthreads();
  float* pacc = (float*)qlds;   // alias: safe via barrier in pool_body
  float* pout = partial + ((size_t)((b * 3 + dt) * 32) + chunk) * 528;
  if (dt == 0)      pool_body<1>(b, chunk, dtok, P, bu, qlds, qil, pacc, pout, tid);
  else if (dt == 1) pool_body<2>(b, chunk, dtok, P, bb, qlds, qil, pacc, pout, tid);
  else              pool_body<3>(b, chunk, dtok, P, bt, qlds, qil, pacc, pout, tid);
}

// ------- fused chunk-reduce + log + query-sum epilogue (one dispatch) -------
__global__ __launch_bounds__(256) void k_finale(const float* __restrict__ partial,
                                                float* __restrict__ out) {
  int idx = blockIdx.x * 256 + threadIdx.x;   // 50688 total
  if (idx >= 32 * 3 * 3 * 11 * 16) return;
  int q = idx & 15;
  int g = idx >> 4;                 // (b,qt,dt,bin), bin fastest
  int bin = g % 11; g /= 11;
  int dt = g % 3; g /= 3;
  int qt = g % 3; int b = g / 3;
  const float* p = partial + ((size_t)(b * 3 + dt) * 32) * 528 + (qt * 16 + q) * 11 + bin;
  float s = 0.f;
#pragma unroll
  for (int c = 0; c < 32; c++) s += p[c * 528];
  float t = (q < 16 - qt) ? 0.01f * logf(fmaxf(s, 1e-10f)) : 0.0f;
#pragma unroll
  for (int off = 1; off < 16; off <<= 1) t += __shfl_xor(t, off);
  if (q == 0) {
    const int p_of[3][3] = {{0, 2, 1}, {3, 5, 6}, {4, 7, 8}};
    out[b * 99 + p_of[qt][dt] * 11 + bin] = t;
  }
}

extern "C" void kernel_launch(void* const* d_in, const int* in_sizes, int n_in,
                              void* d_out, int out_size, void* d_ws, size_t ws_size,
                              hipStream_t stream) {
  const int* qtok = (const int*)d_in[0];
  const int* dtok = (const int*)d_in[1];
  // d_in[2] = batch_semantic: unused by the reference
  const float* wv = (const float*)d_in[3];
  const float* Wu = (const float*)d_in[4];
  const float* bu = (const float*)d_in[5];
  const float* Wb = (const float*)d_in[6];
  const float* bb = (const float*)d_in[7];
  const float* Wt = (const float*)d_in[8];
  const float* bt = (const float*)d_in[9];
  float* out = (float*)d_out;

  // workspace layout (bytes), footprint 148,838,400 (offsets unchanged):
  //   P (fp8): [0, 23,101,440)           30080*768*1   (live: project..pool)
  //   W_bf:    [146,374,656, 146,866,176) 768*320*2    (dead after project)
  //   qvec:    [148,439,040, 148,832,256)
  //   qinv:    [148,832,256, 148,838,400)
  //   partial: [46,202,880, 52,690,944)  3072*528*4
  char* ws = (char*)d_ws;
  unsigned char* P      = (unsigned char*)(ws);
  unsigned short* W_bf  = (unsigned short*)(ws + 146374656);
  unsigned short* qvec  = (unsigned short*)(ws + 148439040);
  float* qinv           = (float*)(ws + 148832256);
  float* partial        = (float*)(ws + 46202880);

  k_convert<<<120, 256, 0, stream>>>(Wu, Wb, Wt, W_bf);
  k_project<<<1440, 256, 0, stream>>>(wv, W_bf, P);
  k_qvec<<<96, 256, 0, stream>>>(qtok, P, bu, bb, bt, qvec, qinv);
  k_pool<<<32 * 96, 256, 0, stream>>>(dtok, P, bu, bb, bt, qvec, qinv, partial);
  k_finale<<<198, 256, 0, stream>>>(partial, out);
}